// Round 2
// baseline (197.499 us; speedup 1.0000x reference)
//
#include <hip/hip_runtime.h>
#include <math.h>

// GaussianRasterizer: H=W=256, N=512.
// d_out layout (all float32): color[H*W*3], radii[N], observe[H*W],
//   plane_depth[H*W], app_opacity[H*W], color_alpha[H*W]
// d_ws: WS struct (depth-sorted SoA), doubles for geometry (decision-critical),
//   floats for color/opacity/z (smooth outputs only).

namespace {
constexpr int HH = 256;
constexpr int WW = 256;
constexpr int NG = 512;
constexpr double FXD = 256.0 / (2.0 * 0.7);
constexpr double FYD = 256.0 / (2.0 * 0.7);
constexpr double LIMXD = 1.3 * 0.7;
constexpr double LIMYD = 1.3 * 0.7;
constexpr double MIN_DEPTH_D = 0.2;
constexpr double ALPHA_MIN_D = 1.0 / 255.0;
}

struct alignas(16) WS {
  double mx[NG];
  double my[NG];
  double cA[NG];
  double cB[NG];
  double cC[NG];
  double thr[NG];  // keep threshold in power domain: log(ALPHA_MIN/opa); 1e300 if invalid
  float z[NG];
  float opa[NG];   // 0 if invalid
  float cr[NG];
  float cg[NG];
  float cb[NG];
};
static_assert(sizeof(WS) == 6 * NG * 8 + 5 * NG * 4, "ws layout");

__global__ __launch_bounds__(NG) void gr_preprocess(
    const float* __restrict__ means, const float* __restrict__ opac,
    const float* __restrict__ cols, const float* __restrict__ scales,
    const float* __restrict__ rots, const float* __restrict__ view,
    float* __restrict__ radii_out, WS* __restrict__ ws) {
  __shared__ double zsh[NG];
  const int i = threadIdx.x;

  // viewmatrix row-major 4x4 (f32 -> f64)
  const double R00 = view[0], R01 = view[1], R02 = view[2], t0 = view[3];
  const double R10 = view[4], R11 = view[5], R12 = view[6], t1 = view[7];
  const double R20 = view[8], R21 = view[9], R22 = view[10], t2 = view[11];

  const double m0 = means[3 * i], m1 = means[3 * i + 1], m2 = means[3 * i + 2];
  const double x = R00 * m0 + R01 * m1 + R02 * m2 + t0;
  const double y = R10 * m0 + R11 * m1 + R12 * m2 + t1;
  const double z = R20 * m0 + R21 * m1 + R22 * m2 + t2;
  const double zc = fmax(z, 0.0001);
  const double txc = fmin(fmax(x / zc, -LIMXD), LIMXD) * zc;
  const double tyc = fmin(fmax(y / zc, -LIMYD), LIMYD) * zc;

  // quaternion (r,x,y,z) -> rotation matrix
  double qr = rots[4 * i], qx = rots[4 * i + 1], qy = rots[4 * i + 2], qz = rots[4 * i + 3];
  const double qn = sqrt(qr * qr + qx * qx + qy * qy + qz * qz);
  qr /= qn; qx /= qn; qy /= qn; qz /= qn;
  const double Rq00 = 1.0 - 2.0 * (qy * qy + qz * qz), Rq01 = 2.0 * (qx * qy - qr * qz), Rq02 = 2.0 * (qx * qz + qr * qy);
  const double Rq10 = 2.0 * (qx * qy + qr * qz), Rq11 = 1.0 - 2.0 * (qx * qx + qz * qz), Rq12 = 2.0 * (qy * qz - qr * qx);
  const double Rq20 = 2.0 * (qx * qz - qr * qy), Rq21 = 2.0 * (qy * qz + qr * qx), Rq22 = 1.0 - 2.0 * (qx * qx + qy * qy);

  // M = Rq * diag(scales); cov3d = M M^T (symmetric)
  const double s0 = scales[3 * i], s1 = scales[3 * i + 1], s2 = scales[3 * i + 2];
  const double M00 = Rq00 * s0, M01 = Rq01 * s1, M02 = Rq02 * s2;
  const double M10 = Rq10 * s0, M11 = Rq11 * s1, M12 = Rq12 * s2;
  const double M20 = Rq20 * s0, M21 = Rq21 * s1, M22 = Rq22 * s2;
  const double C00 = M00 * M00 + M01 * M01 + M02 * M02;
  const double C01 = M00 * M10 + M01 * M11 + M02 * M12;
  const double C02 = M00 * M20 + M01 * M21 + M02 * M22;
  const double C11 = M10 * M10 + M11 * M11 + M12 * M12;
  const double C12 = M10 * M20 + M11 * M21 + M12 * M22;
  const double C22 = M20 * M20 + M21 * M21 + M22 * M22;

  // J (2x3), T = J @ Rw
  const double j00 = FXD / zc, j02 = -FXD * txc / (zc * zc);
  const double j11 = FYD / zc, j12 = -FYD * tyc / (zc * zc);
  const double T00 = j00 * R00 + j02 * R20;
  const double T01 = j00 * R01 + j02 * R21;
  const double T02 = j00 * R02 + j02 * R22;
  const double T10 = j11 * R10 + j12 * R20;
  const double T11 = j11 * R11 + j12 * R21;
  const double T12 = j11 * R12 + j12 * R22;

  // cov2d = T C T^T + 0.3*eye(2)  -- +0.3 on DIAGONAL ONLY (round-1 bug was here)
  const double u0 = C00 * T00 + C01 * T01 + C02 * T02;
  const double u1 = C01 * T00 + C11 * T01 + C12 * T02;
  const double u2 = C02 * T00 + C12 * T01 + C22 * T02;
  const double v0 = C00 * T10 + C01 * T11 + C02 * T12;
  const double v1 = C01 * T10 + C11 * T11 + C12 * T12;
  const double v2 = C02 * T10 + C12 * T11 + C22 * T12;
  const double a = T00 * u0 + T01 * u1 + T02 * u2 + 0.3;
  const double b = T00 * v0 + T01 * v1 + T02 * v2;        // no +0.3
  const double c = T10 * v0 + T11 * v1 + T12 * v2 + 0.3;

  const double det = a * c - b * b;
  const double inv_det = 1.0 / fmax(det, 1e-12);
  const double conA = c * inv_det, conB = -b * inv_det, conC = a * inv_det;
  const double mid = 0.5 * (a + c);
  const double lam1 = mid + sqrt(fmax(mid * mid - det, 0.1));
  const double rad = ceil(3.0 * sqrt(lam1));
  const double mx = FXD * x / zc + 0.5 * (double)WW - 0.5;
  const double my = FYD * y / zc + 0.5 * (double)HH - 0.5;
  const bool valid = (z > MIN_DEPTH_D) && (det > 0.0);
  const double opa_d = (double)opac[i];

  radii_out[i] = (float)rad;  // radii in ORIGINAL order

  // stable depth sort via rank counting (matches stable argsort)
  zsh[i] = z;
  __syncthreads();
  int rank = 0;
  for (int j = 0; j < NG; ++j) {
    const double zj = zsh[j];
    rank += (zj < z) || (zj == z && j < i);
  }

  ws->mx[rank] = mx;
  ws->my[rank] = my;
  ws->cA[rank] = conA;
  ws->cB[rank] = conB;
  ws->cC[rank] = conC;
  // keep decision: alpha >= ALPHA_MIN  <=>  power >= log(ALPHA_MIN/opa) (exp monotone,
  // 0.99 cap > ALPHA_MIN so cap never affects the inequality)
  ws->thr[rank] = valid ? log(ALPHA_MIN_D / opa_d) : 1e300;
  ws->z[rank] = (float)z;
  ws->opa[rank] = valid ? (float)opa_d : 0.f;
  ws->cr[rank] = cols[3 * i];
  ws->cg[rank] = cols[3 * i + 1];
  ws->cb[rank] = cols[3 * i + 2];
}

__global__ __launch_bounds__(256) void gr_rasterize(
    const WS* __restrict__ ws, const float* __restrict__ bg,
    float* __restrict__ out) {
  __shared__ WS sh;
  {
    constexpr int NV4 = (int)(sizeof(WS) / 16);
    const float4* src = reinterpret_cast<const float4*>(ws);
    float4* dst = reinterpret_cast<float4*>(&sh);
    for (int k = threadIdx.x; k < NV4; k += 256) dst[k] = src[k];
  }
  __syncthreads();

  const int p = blockIdx.x * 256 + threadIdx.x;
  const double px = (double)(p & (WW - 1));
  const double py = (double)(p >> 8);

  float T = 1.f, accr = 0.f, accg = 0.f, accb = 0.f, dep = 0.f, mw = 0.f;
  int obs = 0;
  for (int j = 0; j < NG; ++j) {
    const double dx = px - sh.mx[j];
    const double dy = py - sh.my[j];
    const double power = -0.5 * (sh.cA[j] * dx * dx + sh.cC[j] * dy * dy) - sh.cB[j] * dx * dy;
    const bool keep = (power <= 0.0) && (power >= sh.thr[j]);
    const float af = fminf(0.99f, sh.opa[j] * expf((float)fmin(power, 0.0)));
    const float aa = keep ? af : 0.f;
    const float w = aa * T;
    accr += w * sh.cr[j];
    accg += w * sh.cg[j];
    accb += w * sh.cb[j];
    dep += w * sh.z[j];
    mw = fmaxf(mw, w);
    obs += keep ? 1 : 0;
    T *= (1.f - aa);
  }

  out[3 * p]     = accr + T * bg[0];
  out[3 * p + 1] = accg + T * bg[1];
  out[3 * p + 2] = accb + T * bg[2];
  float* ob = out + HH * WW * 3 + NG;
  ob[p]               = (float)obs;
  ob[HH * WW + p]     = dep;
  ob[2 * HH * WW + p] = mw;
  ob[3 * HH * WW + p] = 1.f - T;
}

extern "C" void kernel_launch(void* const* d_in, const int* in_sizes, int n_in,
                              void* d_out, int out_size, void* d_ws, size_t ws_size,
                              hipStream_t stream) {
  const float* means  = (const float*)d_in[0];
  const float* opac   = (const float*)d_in[1];
  const float* cols   = (const float*)d_in[2];
  const float* scales = (const float*)d_in[3];
  const float* rots   = (const float*)d_in[4];
  const float* bg     = (const float*)d_in[5];
  const float* view   = (const float*)d_in[6];
  float* out = (float*)d_out;
  WS* ws = (WS*)d_ws;

  hipLaunchKernelGGL(gr_preprocess, dim3(1), dim3(NG), 0, stream,
                     means, opac, cols, scales, rots, view,
                     out + HH * WW * 3, ws);
  hipLaunchKernelGGL(gr_rasterize, dim3(HH * WW / 256), dim3(256), 0, stream,
                     ws, bg, out);
}

// Round 3
// 128.283 us; speedup vs baseline: 1.5396x; 1.5396x over previous
//
#include <hip/hip_runtime.h>
#include <math.h>

// GaussianRasterizer: H=W=256, N=512.
// d_out (all parsed as float32): color[H*W*3], radii[512], observe[H*W],
//   plane_depth[H*W], app_opacity[H*W], color_alpha[H*W]
//
// Round-3 structure:
//  - preprocess (1 block, 512 thr): f64 per-gaussian math (matches R2 which
//    passed exactly), rank-sort on f32 z, writes depth-sorted AoS f32 records.
//  - rasterize: 1024 blocks x 512 thr. Block = 64 pixels x 8 gaussian-segments
//    (one wave per segment, 64 gaussians each). Wave-uniform AoS reads ->
//    scalar loads. Associative composite combine across segments via LDS.

namespace {
constexpr int HH = 256;
constexpr int WW = 256;
constexpr int NG = 512;
constexpr int SEG = 8;              // waves per block = gaussian segments
constexpr int SEGN = NG / SEG;      // 64 gaussians per segment
constexpr int PIX = 64;             // pixels per block (one lane each)
constexpr double FXD = 256.0 / (2.0 * 0.7);
constexpr double FYD = 256.0 / (2.0 * 0.7);
constexpr double LIMXD = 1.3 * 0.7;
constexpr double LIMYD = 1.3 * 0.7;
constexpr float ALPHA_MIN = (float)(1.0 / 255.0);
}

struct alignas(16) G {  // 48 B, depth-sorted
  float mx, my, A, B, C, opa;  // opa = 0 encodes invalid
  float z, cr, cg, cb, p0, p1;
};

__global__ __launch_bounds__(NG) void gr_preprocess(
    const float* __restrict__ means, const float* __restrict__ opac,
    const float* __restrict__ cols, const float* __restrict__ scales,
    const float* __restrict__ rots, const float* __restrict__ view,
    float* __restrict__ radii_out, G* __restrict__ gs) {
  __shared__ float zsh[NG];
  const int i = threadIdx.x;

  const double R00 = view[0], R01 = view[1], R02 = view[2], t0 = view[3];
  const double R10 = view[4], R11 = view[5], R12 = view[6], t1 = view[7];
  const double R20 = view[8], R21 = view[9], R22 = view[10], t2 = view[11];

  const double m0 = means[3 * i], m1 = means[3 * i + 1], m2 = means[3 * i + 2];
  const double x = R00 * m0 + R01 * m1 + R02 * m2 + t0;
  const double y = R10 * m0 + R11 * m1 + R12 * m2 + t1;
  const double z = R20 * m0 + R21 * m1 + R22 * m2 + t2;
  const double zc = fmax(z, 0.0001);
  const double txc = fmin(fmax(x / zc, -LIMXD), LIMXD) * zc;
  const double tyc = fmin(fmax(y / zc, -LIMYD), LIMYD) * zc;

  double qr = rots[4 * i], qx = rots[4 * i + 1], qy = rots[4 * i + 2], qz = rots[4 * i + 3];
  const double qn = sqrt(qr * qr + qx * qx + qy * qy + qz * qz);
  qr /= qn; qx /= qn; qy /= qn; qz /= qn;
  const double Rq00 = 1.0 - 2.0 * (qy * qy + qz * qz), Rq01 = 2.0 * (qx * qy - qr * qz), Rq02 = 2.0 * (qx * qz + qr * qy);
  const double Rq10 = 2.0 * (qx * qy + qr * qz), Rq11 = 1.0 - 2.0 * (qx * qx + qz * qz), Rq12 = 2.0 * (qy * qz - qr * qx);
  const double Rq20 = 2.0 * (qx * qz - qr * qy), Rq21 = 2.0 * (qy * qz + qr * qx), Rq22 = 1.0 - 2.0 * (qx * qx + qy * qy);

  const double s0 = scales[3 * i], s1 = scales[3 * i + 1], s2 = scales[3 * i + 2];
  const double M00 = Rq00 * s0, M01 = Rq01 * s1, M02 = Rq02 * s2;
  const double M10 = Rq10 * s0, M11 = Rq11 * s1, M12 = Rq12 * s2;
  const double M20 = Rq20 * s0, M21 = Rq21 * s1, M22 = Rq22 * s2;
  const double C00 = M00 * M00 + M01 * M01 + M02 * M02;
  const double C01 = M00 * M10 + M01 * M11 + M02 * M12;
  const double C02 = M00 * M20 + M01 * M21 + M02 * M22;
  const double C11 = M10 * M10 + M11 * M11 + M12 * M12;
  const double C12 = M10 * M20 + M11 * M21 + M12 * M22;
  const double C22 = M20 * M20 + M21 * M21 + M22 * M22;

  const double j00 = FXD / zc, j02 = -FXD * txc / (zc * zc);
  const double j11 = FYD / zc, j12 = -FYD * tyc / (zc * zc);
  const double T00 = j00 * R00 + j02 * R20;
  const double T01 = j00 * R01 + j02 * R21;
  const double T02 = j00 * R02 + j02 * R22;
  const double T10 = j11 * R10 + j12 * R20;
  const double T11 = j11 * R11 + j12 * R21;
  const double T12 = j11 * R12 + j12 * R22;

  // cov2d = T C T^T + 0.3*eye(2) -- diagonal only
  const double u0 = C00 * T00 + C01 * T01 + C02 * T02;
  const double u1 = C01 * T00 + C11 * T01 + C12 * T02;
  const double u2 = C02 * T00 + C12 * T01 + C22 * T02;
  const double v0 = C00 * T10 + C01 * T11 + C02 * T12;
  const double v1 = C01 * T10 + C11 * T11 + C12 * T12;
  const double v2 = C02 * T10 + C12 * T11 + C22 * T12;
  const double a = T00 * u0 + T01 * u1 + T02 * u2 + 0.3;
  const double b = T00 * v0 + T01 * v1 + T02 * v2;
  const double c = T10 * v0 + T11 * v1 + T12 * v2 + 0.3;

  const double det = a * c - b * b;
  const double inv_det = 1.0 / fmax(det, 1e-12);
  const double mid = 0.5 * (a + c);
  const double lam1 = mid + sqrt(fmax(mid * mid - det, 0.1));
  const double rad = ceil(3.0 * sqrt(lam1));
  const double mx = FXD * x / zc + 0.5 * (double)WW - 0.5;
  const double my = FYD * y / zc + 0.5 * (double)HH - 0.5;
  const bool valid = (z > 0.2) && (det > 0.0);

  radii_out[i] = (float)rad;  // original order

  // stable rank-sort on f32 z (matches np f32 stable argsort)
  const float zf = (float)z;
  zsh[i] = zf;
  __syncthreads();
  int rank = 0;
  for (int j = 0; j < NG; ++j) {
    const float zj = zsh[j];
    rank += (zj < zf) || (zj == zf && j < i);
  }

  G g;
  g.mx = (float)mx;
  g.my = (float)my;
  g.A = (float)(c * inv_det);
  g.B = (float)(-b * inv_det);
  g.C = (float)(a * inv_det);
  g.opa = valid ? opac[i] : 0.f;  // opa=0 -> alpha=0 -> keep=false
  g.z = zf;
  g.cr = cols[3 * i];
  g.cg = cols[3 * i + 1];
  g.cb = cols[3 * i + 2];
  g.p0 = 0.f; g.p1 = 0.f;
  gs[rank] = g;
}

__global__ __launch_bounds__(SEG * 64, 8) void gr_rasterize(
    const G* __restrict__ gs, const float* __restrict__ bg,
    float* __restrict__ out) {
  __shared__ float sAr[SEG][PIX], sAg[SEG][PIX], sAb[SEG][PIX];
  __shared__ float sDp[SEG][PIX], sT[SEG][PIX], sMw[SEG][PIX], sOb[SEG][PIX];

  const int tid = threadIdx.x;
  const int wave = tid >> 6;   // segment id
  const int lane = tid & 63;   // pixel-in-block
  const int p = blockIdx.x * PIX + lane;
  const float px = (float)(p & (WW - 1));
  const float py = (float)(p >> 8);

  const G* __restrict__ seg = gs + wave * SEGN;  // wave-uniform base

  float T = 1.f, ar = 0.f, ag = 0.f, ab = 0.f, dep = 0.f, mw = 0.f;
  int obs = 0;
  for (int j = 0; j < SEGN; ++j) {
    const float gmx = seg[j].mx, gmy = seg[j].my;
    const float gA = seg[j].A, gB = seg[j].B, gC = seg[j].C;
    const float gopa = seg[j].opa, gz = seg[j].z;
    const float gcr = seg[j].cr, gcg = seg[j].cg, gcb = seg[j].cb;
    const float dx = px - gmx;
    const float dy = py - gmy;
    const float power = -0.5f * (gA * dx * dx + gC * dy * dy) - gB * dx * dy;
    const float e = __expf(fminf(power, 0.f));
    const float af = fminf(0.99f, gopa * e);
    const bool keep = (power <= 0.f) && (af >= ALPHA_MIN);
    const float aa = keep ? af : 0.f;
    const float w = aa * T;
    ar += w * gcr;
    ag += w * gcg;
    ab += w * gcb;
    dep += w * gz;
    mw = fmaxf(mw, w);
    obs += keep ? 1 : 0;
    T -= aa * T;  // T *= (1 - aa)
  }

  sAr[wave][lane] = ar; sAg[wave][lane] = ag; sAb[wave][lane] = ab;
  sDp[wave][lane] = dep; sT[wave][lane] = T; sMw[wave][lane] = mw;
  sOb[wave][lane] = (float)obs;
  __syncthreads();

  if (tid < PIX) {
    float Tg = 1.f, r = 0.f, g = 0.f, b = 0.f, d = 0.f, m = 0.f, o = 0.f;
    for (int s = 0; s < SEG; ++s) {
      r += Tg * sAr[s][tid];
      g += Tg * sAg[s][tid];
      b += Tg * sAb[s][tid];
      d += Tg * sDp[s][tid];
      m = fmaxf(m, Tg * sMw[s][tid]);
      o += sOb[s][tid];
      Tg *= sT[s][tid];
    }
    out[3 * p] = r + Tg * bg[0];
    out[3 * p + 1] = g + Tg * bg[1];
    out[3 * p + 2] = b + Tg * bg[2];
    float* ob = out + HH * WW * 3 + NG;
    ob[p] = o;
    ob[HH * WW + p] = d;
    ob[2 * HH * WW + p] = m;
    ob[3 * HH * WW + p] = 1.f - Tg;
  }
}

extern "C" void kernel_launch(void* const* d_in, const int* in_sizes, int n_in,
                              void* d_out, int out_size, void* d_ws, size_t ws_size,
                              hipStream_t stream) {
  const float* means  = (const float*)d_in[0];
  const float* opac   = (const float*)d_in[1];
  const float* cols   = (const float*)d_in[2];
  const float* scales = (const float*)d_in[3];
  const float* rots   = (const float*)d_in[4];
  const float* bg     = (const float*)d_in[5];
  const float* view   = (const float*)d_in[6];
  float* out = (float*)d_out;
  G* gs = (G*)d_ws;

  hipLaunchKernelGGL(gr_preprocess, dim3(1), dim3(NG), 0, stream,
                     means, opac, cols, scales, rots, view,
                     out + HH * WW * 3, gs);
  hipLaunchKernelGGL(gr_rasterize, dim3(HH * WW / PIX), dim3(SEG * 64), 0, stream,
                     gs, bg, out);
}

// Round 4
// 87.121 us; speedup vs baseline: 2.2669x; 1.4725x over previous
//
#include <hip/hip_runtime.h>
#include <math.h>

// GaussianRasterizer: H=W=256, N=512.
// d_out (float32): color[H*W*3], radii[512], observe[H*W],
//   plane_depth[H*W], app_opacity[H*W], color_alpha[H*W]
//
// Round-4: tile culling. A pair contributes iff thr <= power <= 0, i.e.
// inside ellipse d^T Q d <= 2*ln(255*opa). Conservative circle:
// r^2 = 2*ln(255*opa)*lam1  (lam1 >= lambda_max(cov2d)).  Skipped pairs have
// alpha=0 & keep=false in the reference => culling is output-identical.
//
//  - preprocess (1 block, 512 thr): unchanged f64 math (passed R2/R3) +
//    cull record (mx, my, (r+0.5)^2) per sorted gaussian.
//  - rasterize: 1024 blocks x 512 thr; block = 16x4 pixel tile; wave w owns
//    sorted segment [64w, 64w+64). Cull via rect-distance + __ballot, walk
//    set bits with __ffsll (uniform -> scalar loads). Segment results
//    combined with associative composite algebra via LDS (as R3).

namespace {
constexpr int HH = 256;
constexpr int WW = 256;
constexpr int NG = 512;
constexpr int SEG = 8;
constexpr int PIX = 64;             // pixels per block (16x4 tile)
constexpr double FXD = 256.0 / (2.0 * 0.7);
constexpr double FYD = 256.0 / (2.0 * 0.7);
constexpr double LIMXD = 1.3 * 0.7;
constexpr double LIMYD = 1.3 * 0.7;
constexpr float ALPHA_MIN = (float)(1.0 / 255.0);
}

struct alignas(16) G {  // 48 B, depth-sorted
  float mx, my, A, B, C, opa;  // opa = 0 encodes invalid
  float z, cr, cg, cb, p0, p1;
};

__global__ __launch_bounds__(NG) void gr_preprocess(
    const float* __restrict__ means, const float* __restrict__ opac,
    const float* __restrict__ cols, const float* __restrict__ scales,
    const float* __restrict__ rots, const float* __restrict__ view,
    float* __restrict__ radii_out, G* __restrict__ gs,
    float4* __restrict__ cull) {
  __shared__ float zsh[NG];
  const int i = threadIdx.x;

  const double R00 = view[0], R01 = view[1], R02 = view[2], t0 = view[3];
  const double R10 = view[4], R11 = view[5], R12 = view[6], t1 = view[7];
  const double R20 = view[8], R21 = view[9], R22 = view[10], t2 = view[11];

  const double m0 = means[3 * i], m1 = means[3 * i + 1], m2 = means[3 * i + 2];
  const double x = R00 * m0 + R01 * m1 + R02 * m2 + t0;
  const double y = R10 * m0 + R11 * m1 + R12 * m2 + t1;
  const double z = R20 * m0 + R21 * m1 + R22 * m2 + t2;
  const double zc = fmax(z, 0.0001);
  const double txc = fmin(fmax(x / zc, -LIMXD), LIMXD) * zc;
  const double tyc = fmin(fmax(y / zc, -LIMYD), LIMYD) * zc;

  double qr = rots[4 * i], qx = rots[4 * i + 1], qy = rots[4 * i + 2], qz = rots[4 * i + 3];
  const double qn = sqrt(qr * qr + qx * qx + qy * qy + qz * qz);
  qr /= qn; qx /= qn; qy /= qn; qz /= qn;
  const double Rq00 = 1.0 - 2.0 * (qy * qy + qz * qz), Rq01 = 2.0 * (qx * qy - qr * qz), Rq02 = 2.0 * (qx * qz + qr * qy);
  const double Rq10 = 2.0 * (qx * qy + qr * qz), Rq11 = 1.0 - 2.0 * (qx * qx + qz * qz), Rq12 = 2.0 * (qy * qz - qr * qx);
  const double Rq20 = 2.0 * (qx * qz - qr * qy), Rq21 = 2.0 * (qy * qz + qr * qx), Rq22 = 1.0 - 2.0 * (qx * qx + qy * qy);

  const double s0 = scales[3 * i], s1 = scales[3 * i + 1], s2 = scales[3 * i + 2];
  const double M00 = Rq00 * s0, M01 = Rq01 * s1, M02 = Rq02 * s2;
  const double M10 = Rq10 * s0, M11 = Rq11 * s1, M12 = Rq12 * s2;
  const double M20 = Rq20 * s0, M21 = Rq21 * s1, M22 = Rq22 * s2;
  const double C00 = M00 * M00 + M01 * M01 + M02 * M02;
  const double C01 = M00 * M10 + M01 * M11 + M02 * M12;
  const double C02 = M00 * M20 + M01 * M21 + M02 * M22;
  const double C11 = M10 * M10 + M11 * M11 + M12 * M12;
  const double C12 = M10 * M20 + M11 * M21 + M12 * M22;
  const double C22 = M20 * M20 + M21 * M21 + M22 * M22;

  const double j00 = FXD / zc, j02 = -FXD * txc / (zc * zc);
  const double j11 = FYD / zc, j12 = -FYD * tyc / (zc * zc);
  const double T00 = j00 * R00 + j02 * R20;
  const double T01 = j00 * R01 + j02 * R21;
  const double T02 = j00 * R02 + j02 * R22;
  const double T10 = j11 * R10 + j12 * R20;
  const double T11 = j11 * R11 + j12 * R21;
  const double T12 = j11 * R12 + j12 * R22;

  // cov2d = T C T^T + 0.3*eye(2) -- diagonal only
  const double u0 = C00 * T00 + C01 * T01 + C02 * T02;
  const double u1 = C01 * T00 + C11 * T01 + C12 * T02;
  const double u2 = C02 * T00 + C12 * T01 + C22 * T02;
  const double v0 = C00 * T10 + C01 * T11 + C02 * T12;
  const double v1 = C01 * T10 + C11 * T11 + C12 * T12;
  const double v2 = C02 * T10 + C12 * T11 + C22 * T12;
  const double a = T00 * u0 + T01 * u1 + T02 * u2 + 0.3;
  const double b = T00 * v0 + T01 * v1 + T02 * v2;
  const double c = T10 * v0 + T11 * v1 + T12 * v2 + 0.3;

  const double det = a * c - b * b;
  const double inv_det = 1.0 / fmax(det, 1e-12);
  const double mid = 0.5 * (a + c);
  const double lam1 = mid + sqrt(fmax(mid * mid - det, 0.1));  // >= lambda_max
  const double rad = ceil(3.0 * sqrt(lam1));
  const double mx = FXD * x / zc + 0.5 * (double)WW - 0.5;
  const double my = FYD * y / zc + 0.5 * (double)HH - 0.5;
  const bool valid = (z > 0.2) && (det > 0.0);

  radii_out[i] = (float)rad;  // original order

  // stable rank-sort on f32 z
  const float zf = (float)z;
  zsh[i] = zf;
  __syncthreads();
  int rank = 0;
  for (int j = 0; j < NG; ++j) {
    const float zj = zsh[j];
    rank += (zj < zf) || (zj == zf && j < i);
  }

  G g;
  g.mx = (float)mx;
  g.my = (float)my;
  g.A = (float)(c * inv_det);
  g.B = (float)(-b * inv_det);
  g.C = (float)(a * inv_det);
  g.opa = valid ? opac[i] : 0.f;
  g.z = zf;
  g.cr = cols[3 * i];
  g.cg = cols[3 * i + 1];
  g.cb = cols[3 * i + 2];
  g.p0 = 0.f; g.p1 = 0.f;
  gs[rank] = g;

  // conservative cull circle: keep possible only if |d|^2 <= 2*ln(255*opa)*lam1
  float4 cl;
  cl.x = (float)mx;
  cl.y = (float)my;
  const double opa_d = (double)opac[i];
  if (valid && 255.0 * opa_d > 1.0) {
    const double rc = sqrt(2.0 * log(255.0 * opa_d) * lam1) + 0.5;  // +0.5px margin
    cl.z = (float)(rc * rc);
  } else {
    cl.z = -1.f;  // never intersects
  }
  cl.w = 0.f;
  cull[rank] = cl;
}

__global__ __launch_bounds__(SEG * 64, 8) void gr_rasterize(
    const G* __restrict__ gs, const float4* __restrict__ cull,
    const float* __restrict__ bg, float* __restrict__ out) {
  __shared__ float sAr[SEG][PIX], sAg[SEG][PIX], sAb[SEG][PIX];
  __shared__ float sDp[SEG][PIX], sT[SEG][PIX], sMw[SEG][PIX], sOb[SEG][PIX];

  const int tid = threadIdx.x;
  const int wave = tid >> 6;
  const int lane = tid & 63;

  // 16x4 tile: 16 tiles across, 64 down
  const int tx = blockIdx.x & 15;
  const int ty = blockIdx.x >> 4;
  const int pxi = (tx << 4) | (lane & 15);
  const int pyi = (ty << 2) | (lane >> 4);
  const int p = (pyi << 8) | pxi;
  const float px = (float)pxi;
  const float py = (float)pyi;

  // cull my segment's gaussian #lane against the tile rect
  const float4 cr4 = cull[(wave << 6) | lane];
  const float x0 = (float)(tx << 4), x1 = x0 + 15.f;
  const float y0 = (float)(ty << 2), y1 = y0 + 3.f;
  const float ddx = fmaxf(fmaxf(x0 - cr4.x, cr4.x - x1), 0.f);
  const float ddy = fmaxf(fmaxf(y0 - cr4.y, cr4.y - y1), 0.f);
  unsigned long long mask = __ballot(ddx * ddx + ddy * ddy <= cr4.z);

  const G* __restrict__ seg = gs + (wave << 6);
  float T = 1.f, ar = 0.f, ag = 0.f, ab = 0.f, dep = 0.f, mw = 0.f;
  int obs = 0;
  while (mask) {
    const int j = __ffsll(mask) - 1;  // uniform -> scalar loads below
    mask &= mask - 1;
    const float gmx = seg[j].mx, gmy = seg[j].my;
    const float gA = seg[j].A, gB = seg[j].B, gC = seg[j].C;
    const float gopa = seg[j].opa, gz = seg[j].z;
    const float gcr = seg[j].cr, gcg = seg[j].cg, gcb = seg[j].cb;
    const float dx = px - gmx;
    const float dy = py - gmy;
    const float power = -0.5f * (gA * dx * dx + gC * dy * dy) - gB * dx * dy;
    const float e = __expf(fminf(power, 0.f));
    const float af = fminf(0.99f, gopa * e);
    const bool keep = (power <= 0.f) && (af >= ALPHA_MIN);
    const float aa = keep ? af : 0.f;
    const float w = aa * T;
    ar += w * gcr;
    ag += w * gcg;
    ab += w * gcb;
    dep += w * gz;
    mw = fmaxf(mw, w);
    obs += keep ? 1 : 0;
    T -= aa * T;
  }

  sAr[wave][lane] = ar; sAg[wave][lane] = ag; sAb[wave][lane] = ab;
  sDp[wave][lane] = dep; sT[wave][lane] = T; sMw[wave][lane] = mw;
  sOb[wave][lane] = (float)obs;
  __syncthreads();

  if (tid < PIX) {
    const int pxi2 = (tx << 4) | (tid & 15);
    const int pyi2 = (ty << 2) | (tid >> 4);
    const int pp = (pyi2 << 8) | pxi2;
    float Tg = 1.f, r = 0.f, g = 0.f, b = 0.f, d = 0.f, m = 0.f, o = 0.f;
    for (int s = 0; s < SEG; ++s) {
      r += Tg * sAr[s][tid];
      g += Tg * sAg[s][tid];
      b += Tg * sAb[s][tid];
      d += Tg * sDp[s][tid];
      m = fmaxf(m, Tg * sMw[s][tid]);
      o += sOb[s][tid];
      Tg *= sT[s][tid];
    }
    out[3 * pp] = r + Tg * bg[0];
    out[3 * pp + 1] = g + Tg * bg[1];
    out[3 * pp + 2] = b + Tg * bg[2];
    float* ob = out + HH * WW * 3 + NG;
    ob[pp] = o;
    ob[HH * WW + pp] = d;
    ob[2 * HH * WW + pp] = m;
    ob[3 * HH * WW + pp] = 1.f - Tg;
  }
}

extern "C" void kernel_launch(void* const* d_in, const int* in_sizes, int n_in,
                              void* d_out, int out_size, void* d_ws, size_t ws_size,
                              hipStream_t stream) {
  const float* means  = (const float*)d_in[0];
  const float* opac   = (const float*)d_in[1];
  const float* cols   = (const float*)d_in[2];
  const float* scales = (const float*)d_in[3];
  const float* rots   = (const float*)d_in[4];
  const float* bg     = (const float*)d_in[5];
  const float* view   = (const float*)d_in[6];
  float* out = (float*)d_out;
  G* gs = (G*)d_ws;
  float4* cull = (float4*)((char*)d_ws + NG * sizeof(G));

  hipLaunchKernelGGL(gr_preprocess, dim3(1), dim3(NG), 0, stream,
                     means, opac, cols, scales, rots, view,
                     out + HH * WW * 3, gs, cull);
  hipLaunchKernelGGL(gr_rasterize, dim3(HH * WW / PIX), dim3(SEG * 64), 0, stream,
                     gs, cull, bg, out);
}